// Round 5
// baseline (419.544 us; speedup 1.0000x reference)
//
#include <hip/hip_runtime.h>
#include <hip/hip_fp16.h>
#include <math.h>

#define N_NODES 100000
#define N_EDGES 3200000
#define DIM 16
#define NSZ (N_NODES * DIM)

#define NPB 32          // nodes per bucket (bucket = col>>5, cl = col&31)
#define NBUCK 3125      // 100000/32 exactly -> no partial bucket
#define CAP 1536        // aggregate LDS edge capacity (mean 1024, ~+16 sigma)
#define PRK 3           // ceil(CAP/512) register-carried entries per thread

// packed entry: [63:47]=col(17) [46:30]=row(17) [29:0]=w bits>>2
typedef float nvec4 __attribute__((ext_vector_type(4)));

// ---- 1) prep: f32 state -> f16 (sin,cos) table; out1=x, out2=-x;
//         per-bucket histogram (LDS) -> global totals ----
__global__ __launch_bounds__(512)
void prep(const float* __restrict__ state, const int* __restrict__ col,
          float* __restrict__ scp, float* __restrict__ out,
          int* __restrict__ totals) {
    __shared__ int hcnt[NBUCK];                 // 12.5 KB
    int t = threadIdx.x;
    int gid = blockIdx.x * 512 + t;
    int gsz = gridDim.x * 512;
    for (int j = t; j < NBUCK; j += 512) hcnt[j] = 0;
    for (int i = gid; i < NSZ / 4; i += gsz) {
        nvec4 v = __builtin_nontemporal_load(&((const nvec4*)state)[i]);
        union { __half2 h[4]; nvec4 f; } u;
        u.h[0] = __floats2half2_rn(__sinf(v.x), __cosf(v.x));
        u.h[1] = __floats2half2_rn(__sinf(v.y), __cosf(v.y));
        u.h[2] = __floats2half2_rn(__sinf(v.z), __cosf(v.z));
        u.h[3] = __floats2half2_rn(__sinf(v.w), __cosf(v.w));
        ((nvec4*)scp)[i] = u.f;                 // keep cached (reused by aggregate)
        __builtin_nontemporal_store(v, &((nvec4*)(out + 1 * (size_t)NSZ))[i]);
        nvec4 nv = {-v.x, -v.y, -v.z, -v.w};
        __builtin_nontemporal_store(nv, &((nvec4*)(out + 2 * (size_t)NSZ))[i]);
    }
    __syncthreads();
    for (int i = gid; i < N_EDGES / 4; i += gsz) {
        int4 c = ((const int4*)col)[i];
        atomicAdd(&hcnt[c.x >> 5], 1);
        atomicAdd(&hcnt[c.y >> 5], 1);
        atomicAdd(&hcnt[c.z >> 5], 1);
        atomicAdd(&hcnt[c.w >> 5], 1);
    }
    __syncthreads();
    for (int j = t; j < NBUCK; j += 512) {
        int c = hcnt[j];
        if (c) atomicAdd(&totals[j], c);
    }
}

// ---- 2) exclusive scan of 3125 totals -> off[3126]; init gcur = off ----
__global__ __launch_bounds__(1024)
void scan_off(const int* __restrict__ totals, int* __restrict__ off,
              int* __restrict__ gcur) {
    __shared__ int wsum[16];
    int t = threadIdx.x;
    int base = t * 4;
    int v0 = (base + 0 < NBUCK) ? totals[base + 0] : 0;
    int v1 = (base + 1 < NBUCK) ? totals[base + 1] : 0;
    int v2 = (base + 2 < NBUCK) ? totals[base + 2] : 0;
    int v3 = (base + 3 < NBUCK) ? totals[base + 3] : 0;
    int s = v0 + v1 + v2 + v3;
    int ps = s;
    #pragma unroll
    for (int d = 1; d < 64; d <<= 1) {
        int u = __shfl_up(ps, d, 64);
        if ((t & 63) >= d) ps += u;
    }
    if ((t & 63) == 63) wsum[t >> 6] = ps;
    __syncthreads();
    int wid = t >> 6, wbase = 0;
    #pragma unroll
    for (int k = 0; k < 16; ++k) wbase += (k < wid) ? wsum[k] : 0;
    int o0 = wbase + ps - s;
    int o1 = o0 + v0, o2 = o1 + v1, o3 = o2 + v2;
    if (base     <= NBUCK) off[base]     = o0;
    if (base + 1 <= NBUCK) off[base + 1] = o1;
    if (base + 2 <= NBUCK) off[base + 2] = o2;
    if (base + 3 <= NBUCK) off[base + 3] = o3;
    if (base     < NBUCK) gcur[base]     = o0;
    if (base + 1 < NBUCK) gcur[base + 1] = o1;
    if (base + 2 < NBUCK) gcur[base + 2] = o2;
    if (base + 3 < NBUCK) gcur[base + 3] = o3;
}

// ---- 3) scatter: slot reservation by global atomic cursor; order within
//         bucket irrelevant (aggregate re-sorts by cl). ----
__global__ __launch_bounds__(256)
void scatter(const int* __restrict__ row, const int* __restrict__ col,
             const float* __restrict__ w, int* __restrict__ gcur,
             unsigned long long* __restrict__ packed) {
    int gid = blockIdx.x * 256 + threadIdx.x;
    int gsz = gridDim.x * 256;
    for (int i = gid; i < N_EDGES / 4; i += gsz) {
        int4 c = ((const int4*)col)[i];
        int4 r = ((const int4*)row)[i];
        float4 ww = ((const float4*)w)[i];
        int pos;
        pos = atomicAdd(&gcur[c.x >> 5], 1);
        packed[pos] = ((unsigned long long)(unsigned)c.x << 47)
                    | ((unsigned long long)(unsigned)r.x << 30)
                    | (unsigned long long)(__float_as_uint(ww.x) >> 2);
        pos = atomicAdd(&gcur[c.y >> 5], 1);
        packed[pos] = ((unsigned long long)(unsigned)c.y << 47)
                    | ((unsigned long long)(unsigned)r.y << 30)
                    | (unsigned long long)(__float_as_uint(ww.y) >> 2);
        pos = atomicAdd(&gcur[c.z >> 5], 1);
        packed[pos] = ((unsigned long long)(unsigned)c.z << 47)
                    | ((unsigned long long)(unsigned)r.z << 30)
                    | (unsigned long long)(__float_as_uint(ww.z) >> 2);
        pos = atomicAdd(&gcur[c.w >> 5], 1);
        packed[pos] = ((unsigned long long)(unsigned)c.w << 47)
                    | ((unsigned long long)(unsigned)r.w << 30)
                    | (unsigned long long)(__float_as_uint(ww.w) >> 2);
    }
}

// S += w*sin_r, C += w*cos_r for 4 dims (lane q of a node group)
__device__ inline void acc_sc(float4& S, float4& C, unsigned long long p,
                              nvec4 h) {
    float we = __uint_as_float(((unsigned)p & 0x3FFFFFFFu) << 2);
    union { nvec4 f; __half2 h2[4]; } uu; uu.f = h;
    float2 f0 = __half22float2(uu.h2[0]);
    float2 f1 = __half22float2(uu.h2[1]);
    float2 f2 = __half22float2(uu.h2[2]);
    float2 f3 = __half22float2(uu.h2[3]);
    S.x += we * f0.x; C.x += we * f0.y;
    S.y += we * f1.x; C.y += we * f1.y;
    S.z += we * f2.x; C.z += we * f2.y;
    S.w += we * f3.x; C.w += we * f3.y;
}

// ---- 4) aggregate: 512 thr = 32 nodes x 4 dim-lanes x 4 edge-subgroups.
//         NBUCK=3125 blocks (12.2/CU -> quantization ~1.07), 4 blocks/CU. ----
__global__ __launch_bounds__(512, 8)
void aggregate(const float* __restrict__ state, const float* __restrict__ scp,
               const int* __restrict__ off,
               const unsigned long long* __restrict__ packed,
               float* __restrict__ out) {
    __shared__ unsigned long long sbuf[CAP];       // 12,288 B cl-sorted edges
    __shared__ nvec4 stage[3 * NPB * 4];           // 6,144 B epilogue staging
    __shared__ int s_cnt[NPB], s_start[NPB], s_cur[NPB];
    int b = blockIdx.x, t = threadIdx.x;
    int q = t & 3, sub = (t >> 2) & 3, g = t >> 4;   // node group 0..31
    int beg = off[b], end = off[b + 1];
    int n = b * NPB + g;                              // always < 100000
    float4 xx = ((const float4*)state)[n * 4 + q];
    float4 S = {0.f, 0.f, 0.f, 0.f}, C = {0.f, 0.f, 0.f, 0.f};
    const nvec4* scp4 = (const nvec4*)scp;

    for (int tbeg = beg; tbeg < end; tbeg += CAP) {
        int tend = tbeg + CAP; if (tend > end) tend = end;
        if (t < NPB) s_cnt[t] = 0;
        __syncthreads();

        // phase 1: coalesced read into registers; LDS cl-histogram
        unsigned long long pr[PRK];
        #pragma unroll
        for (int k = 0; k < PRK; ++k) {
            int e = tbeg + t + k * 512;
            if (e < tend) {
                pr[k] = __builtin_nontemporal_load(&packed[e]);
                atomicAdd(&s_cnt[(unsigned)(pr[k] >> 47) & 31u], 1);
            }
        }
        __syncthreads();

        // phase 2: 32-entry exclusive scan on first wave
        if (t < 32) {
            int v = s_cnt[t], ps = v;
            #pragma unroll
            for (int d = 1; d < 32; d <<= 1) {
                int uu = __shfl_up(ps, d, 64);
                if (t >= d) ps += uu;
            }
            s_start[t] = ps - v;
            s_cur[t] = ps - v;
        }
        __syncthreads();

        // phase 3: scatter from registers
        #pragma unroll
        for (int k = 0; k < PRK; ++k) {
            int e = tbeg + t + k * 512;
            if (e < tend) {
                int cl = (int)((pr[k] >> 47) & 31u);
                int pos = atomicAdd(&s_cur[cl], 1);
                sbuf[pos] = pr[k];
            }
        }
        __syncthreads();

        // phase 4: owner-computes; subgroup takes every 4th edge, unroll-4
        {
            int es = s_start[g], ee = s_cur[g];
            int e = es + sub;
            for (; e + 12 < ee; e += 16) {
                unsigned long long p0 = sbuf[e];
                unsigned long long p1 = sbuf[e + 4];
                unsigned long long p2 = sbuf[e + 8];
                unsigned long long p3 = sbuf[e + 12];
                nvec4 h0 = scp4[(unsigned)((p0 >> 30) & 0x1FFFFu) * 4u + q];
                nvec4 h1 = scp4[(unsigned)((p1 >> 30) & 0x1FFFFu) * 4u + q];
                nvec4 h2 = scp4[(unsigned)((p2 >> 30) & 0x1FFFFu) * 4u + q];
                nvec4 h3 = scp4[(unsigned)((p3 >> 30) & 0x1FFFFu) * 4u + q];
                acc_sc(S, C, p0, h0);
                acc_sc(S, C, p1, h1);
                acc_sc(S, C, p2, h2);
                acc_sc(S, C, p3, h3);
            }
            for (; e < ee; e += 4) {
                unsigned long long p0 = sbuf[e];
                nvec4 h0 = scp4[(unsigned)((p0 >> 30) & 0x1FFFFu) * 4u + q];
                acc_sc(S, C, p0, h0);
            }
        }
        __syncthreads();
    }

    // merge 4 subgroups (lanes t^4, t^8 — same wave)
    S.x += __shfl_xor(S.x, 4, 64); S.y += __shfl_xor(S.y, 4, 64);
    S.z += __shfl_xor(S.z, 4, 64); S.w += __shfl_xor(S.w, 4, 64);
    C.x += __shfl_xor(C.x, 4, 64); C.y += __shfl_xor(C.y, 4, 64);
    C.z += __shfl_xor(C.z, 4, 64); C.w += __shfl_xor(C.w, 4, 64);
    S.x += __shfl_xor(S.x, 8, 64); S.y += __shfl_xor(S.y, 8, 64);
    S.z += __shfl_xor(S.z, 8, 64); S.w += __shfl_xor(S.w, 8, 64);
    C.x += __shfl_xor(C.x, 8, 64); C.y += __shfl_xor(C.y, 8, 64);
    C.z += __shfl_xor(C.z, 8, 64); C.w += __shfl_xor(C.w, 8, 64);

    if (sub == 0) {
        // agg = cos(x_c)*S - sin(x_c)*C  (f32 sincos of f32 state)
        float4 agg, th;
        float sx, cx;
        sx = __sinf(xx.x); cx = __cosf(xx.x); agg.x = cx * S.x - sx * C.x;
        sx = __sinf(xx.y); cx = __cosf(xx.y); agg.y = cx * S.y - sx * C.y;
        sx = __sinf(xx.z); cx = __cosf(xx.z); agg.z = cx * S.z - sx * C.z;
        sx = __sinf(xx.w); cx = __cosf(xx.w); agg.w = cx * S.w - sx * C.w;
        th.x = tanhf(agg.x); th.y = tanhf(agg.y);
        th.z = tanhf(agg.z); th.w = tanhf(agg.w);
        int slot = g * 4 + q;                         // 0..127
        stage[0 * 128 + slot] = (nvec4){th.x - xx.x, th.y - xx.y,
                                        th.z - xx.z, th.w - xx.w};
        stage[1 * 128 + slot] = (nvec4){agg.x, agg.y, agg.z, agg.w};
        stage[2 * 128 + slot] = (nvec4){th.x, th.y, th.z, th.w};
    }
    __syncthreads();
    if (t < 384) {                                    // full-density burst write
        int a = t >> 7, j = t & 127;
        nvec4 v = stage[t];
        size_t arr = (a == 0) ? 0 : ((a == 1) ? 3 : 4);
        __builtin_nontemporal_store(
            v, &((nvec4*)(out + arr * (size_t)NSZ))[b * 128 + j]);
    }
}

// ---- fallback (tiny ws): atomic path ----
__global__ __launch_bounds__(256)
void edge_kernel(const float* __restrict__ state, const int* __restrict__ row,
                 const int* __restrict__ col, const float* __restrict__ w,
                 float* __restrict__ agg) {
    int idx = blockIdx.x * blockDim.x + threadIdx.x;
    if (idx >= N_EDGES * 4) return;
    int e = idx >> 2, qq = idx & 3;
    int r = row[e], c = col[e];
    float we = w[e];
    const float4 xr = ((const float4*)state)[r * 4 + qq];
    const float4 xcv = ((const float4*)state)[c * 4 + qq];
    float* dst = agg + c * DIM + qq * 4;
    atomicAdd(dst + 0, sinf(xr.x - xcv.x) * we);
    atomicAdd(dst + 1, sinf(xr.y - xcv.y) * we);
    atomicAdd(dst + 2, sinf(xr.z - xcv.z) * we);
    atomicAdd(dst + 3, sinf(xr.w - xcv.w) * we);
}

__global__ __launch_bounds__(256)
void node_kernel(const float* __restrict__ state, const float* __restrict__ agg,
                 float* __restrict__ out) {
    int idx = blockIdx.x * blockDim.x + threadIdx.x;
    if (idx >= N_NODES * 4) return;
    float4 x = ((const float4*)state)[idx];
    float4 a = ((const float4*)agg)[idx];
    float4 tv = make_float4(tanhf(a.x), tanhf(a.y), tanhf(a.z), tanhf(a.w));
    ((float4*)(out + 0 * NSZ))[idx] = make_float4(tv.x - x.x, tv.y - x.y,
                                                  tv.z - x.z, tv.w - x.w);
    ((float4*)(out + 1 * NSZ))[idx] = x;
    ((float4*)(out + 2 * NSZ))[idx] = make_float4(-x.x, -x.y, -x.z, -x.w);
    ((float4*)(out + 4 * NSZ))[idx] = tv;
}

extern "C" void kernel_launch(void* const* d_in, const int* in_sizes, int n_in,
                              void* d_out, int out_size, void* d_ws, size_t ws_size,
                              hipStream_t stream) {
    const float* state = (const float*)d_in[0];
    const int*   row   = (const int*)d_in[1];
    const int*   col   = (const int*)d_in[2];
    const float* w     = (const float*)d_in[3];
    float* out = (float*)d_out;

    // ws: packed | scp (f16 sincos) | totals | off | gcur
    size_t packed_off = 0;
    size_t scp_off    = packed_off + (size_t)N_EDGES * 8;          // 25.6MB
    size_t tot_off    = scp_off + (size_t)NSZ * 4;                 // +6.4MB
    size_t off_off    = tot_off + ((size_t)NBUCK * 4 + 15) / 16 * 16;
    size_t gcur_off   = off_off + ((size_t)(NBUCK + 1) * 4 + 15) / 16 * 16;
    size_t needed     = gcur_off + (size_t)NBUCK * 4;

    if (ws_size >= needed) {
        unsigned long long* packed =
            (unsigned long long*)((char*)d_ws + packed_off);
        float* scp  = (float*)((char*)d_ws + scp_off);
        int* totals = (int*)((char*)d_ws + tot_off);
        int* off    = (int*)((char*)d_ws + off_off);
        int* gcur   = (int*)((char*)d_ws + gcur_off);

        (void)hipMemsetAsync(totals, 0, (size_t)NBUCK * sizeof(int), stream);
        prep<<<512, 512, 0, stream>>>(state, col, scp, out, totals);
        scan_off<<<1, 1024, 0, stream>>>(totals, off, gcur);
        scatter<<<1024, 256, 0, stream>>>(row, col, w, gcur, packed);
        aggregate<<<NBUCK, 512, 0, stream>>>(state, scp, off, packed, out);
    } else {
        float* agg = out + 3 * NSZ;
        (void)hipMemsetAsync(agg, 0, NSZ * sizeof(float), stream);
        edge_kernel<<<(N_EDGES * 4 + 255) / 256, 256, 0, stream>>>(
            state, row, col, w, agg);
        node_kernel<<<(N_NODES * 4 + 255) / 256, 256, 0, stream>>>(
            state, agg, out);
    }
}

// Round 7
// 200.449 us; speedup vs baseline: 2.0930x; 2.0930x over previous
//
#include <hip/hip_runtime.h>
#include <hip/hip_fp16.h>
#include <math.h>

#define N_NODES 100000
#define N_EDGES 3200000
#define DIM 16
#define NSZ (N_NODES * DIM)

#define NPB 32          // nodes per fine bucket (fine = col>>5, cl = col&31)
#define NBUCK_F 3125    // fine buckets: 100000/32 exactly
#define NBUCK_C 782     // coarse buckets (col>>7, 128 nodes) for the radix sort
#define NBLK 512        // sort partition blocks
#define EPB 6256        // edges per partition block; multiple of 4 for int4
#define CAP 1536        // aggregate LDS tile (of the coarse range)
#define PRK 3           // CAP/512 register-carried entries per thread
#define OFFMAX (NBUCK_F + 3)   // off[] valid indices 0..3128 (pads = N_EDGES)

// packed entry: [63:47]=col(17) [46:30]=row(17) [29:0]=w bits>>2
typedef float nvec4 __attribute__((ext_vector_type(4)));

// ---- 1) prep: f32 state -> f16 (sin,cos) table; out1=x, out2=-x;
//         per-block FINE histogram -> coarse tbl[bucket][blk] + fine totals ----
__global__ __launch_bounds__(512)
void prep(const float* __restrict__ state, const int* __restrict__ col,
          float* __restrict__ scp, float* __restrict__ out,
          unsigned* __restrict__ tbl, int* __restrict__ totals) {
    __shared__ int hcnt[NBUCK_F + 3];           // pad to 3128 for quad sums
    int t = threadIdx.x, blk = blockIdx.x;
    for (int j = t; j < NBUCK_F + 3; j += 512) hcnt[j] = 0;
    int gid = blk * 512 + t, gsz = NBLK * 512;
    for (int i = gid; i < NSZ / 4; i += gsz) {
        nvec4 v = __builtin_nontemporal_load(&((const nvec4*)state)[i]);
        union { __half2 h[4]; nvec4 f; } u;
        u.h[0] = __floats2half2_rn(__sinf(v.x), __cosf(v.x));
        u.h[1] = __floats2half2_rn(__sinf(v.y), __cosf(v.y));
        u.h[2] = __floats2half2_rn(__sinf(v.z), __cosf(v.z));
        u.h[3] = __floats2half2_rn(__sinf(v.w), __cosf(v.w));
        ((nvec4*)scp)[i] = u.f;                 // reused by aggregate: keep cached
        __builtin_nontemporal_store(v, &((nvec4*)(out + 1 * (size_t)NSZ))[i]);
        nvec4 nv = {-v.x, -v.y, -v.z, -v.w};
        __builtin_nontemporal_store(nv, &((nvec4*)(out + 2 * (size_t)NSZ))[i]);
    }
    __syncthreads();
    int e0 = blk * EPB;
    int eN = e0 + EPB; if (eN > N_EDGES) eN = N_EDGES;
    int nch = (eN - e0) >> 2;
    const int4* c4p = (const int4*)(col + e0);
    for (int i = t; i < nch; i += 512) {
        int4 c = c4p[i];
        atomicAdd(&hcnt[c.x >> 5], 1);
        atomicAdd(&hcnt[c.y >> 5], 1);
        atomicAdd(&hcnt[c.z >> 5], 1);
        atomicAdd(&hcnt[c.w >> 5], 1);
    }
    __syncthreads();
    for (int j = t; j < NBUCK_C; j += 512) {    // coarse per-block counts
        int c = hcnt[4 * j] + hcnt[4 * j + 1] + hcnt[4 * j + 2] + hcnt[4 * j + 3];
        tbl[(size_t)j * NBLK + blk] = (unsigned)c;
    }
    for (int j = t; j < NBUCK_F; j += 512) {    // fine totals
        int c = hcnt[j];
        if (c) atomicAdd(&totals[j], c);
    }
}

// ---- 2) exclusive scan of 3125 fine totals -> off[0..3128]
//         (indices 3126..3128 padded with the grand total) ----
__global__ __launch_bounds__(1024)
void scan_off(const int* __restrict__ totals, int* __restrict__ off) {
    __shared__ int wsum[16];
    int t = threadIdx.x;
    int base = t * 4;
    int v0 = (base + 0 < NBUCK_F) ? totals[base + 0] : 0;
    int v1 = (base + 1 < NBUCK_F) ? totals[base + 1] : 0;
    int v2 = (base + 2 < NBUCK_F) ? totals[base + 2] : 0;
    int v3 = (base + 3 < NBUCK_F) ? totals[base + 3] : 0;
    int s = v0 + v1 + v2 + v3;
    int ps = s;
    #pragma unroll
    for (int d = 1; d < 64; d <<= 1) {
        int u = __shfl_up(ps, d, 64);
        if ((t & 63) >= d) ps += u;
    }
    if ((t & 63) == 63) wsum[t >> 6] = ps;
    __syncthreads();
    int wid = t >> 6, wbase = 0;
    #pragma unroll
    for (int k = 0; k < 16; ++k) wbase += (k < wid) ? wsum[k] : 0;
    int o0 = wbase + ps - s;
    int o1 = o0 + v0, o2 = o1 + v1, o3 = o2 + v2;
    if (base     <= OFFMAX) off[base]     = o0;
    if (base + 1 <= OFFMAX) off[base + 1] = o1;
    if (base + 2 <= OFFMAX) off[base + 2] = o2;
    if (base + 3 <= OFFMAX) off[base + 3] = o3;
}

// ---- 3) tbl counts -> global write bases, in place (shfl scan) ----
__global__ __launch_bounds__(512)
void base_scan(unsigned* __restrict__ tbl, const int* __restrict__ off) {
    __shared__ int wsum[8];
    int b = blockIdx.x, t = threadIdx.x;
    int v = (int)tbl[(size_t)b * NBLK + t];
    int ps = v;
    #pragma unroll
    for (int d = 1; d < 64; d <<= 1) {
        int u = __shfl_up(ps, d, 64);
        if ((t & 63) >= d) ps += u;
    }
    if ((t & 63) == 63) wsum[t >> 6] = ps;
    __syncthreads();
    int wid = t >> 6, wbase = 0;
    #pragma unroll
    for (int k = 0; k < 8; ++k) wbase += (k < wid) ? wsum[k] : 0;
    tbl[(size_t)b * NBLK + t] = (unsigned)(off[4 * b] + wbase + ps - v); // excl
}

// ---- 4) sort_write: per-block LDS radix to COARSE buckets, dense sweep
//         writes runs of ~8 entries (full cache lines) ----
__global__ __launch_bounds__(512)
void sort_write(const int* __restrict__ row, const int* __restrict__ col,
                const float* __restrict__ w, const unsigned* __restrict__ tbl,
                const int* __restrict__ off,
                unsigned long long* __restrict__ packed) {
    __shared__ unsigned long long sbuf[EPB];   // 50,048 B
    __shared__ int sc[1024];                   // lstart (persist for sweep)
    __shared__ int cur[NBUCK_C];               // counts -> scatter cursor
    __shared__ int gbase[NBUCK_C];
    __shared__ int wsum[8];
    int t = threadIdx.x, blk = blockIdx.x;
    int e0 = blk * EPB;
    int eN = e0 + EPB; if (eN > N_EDGES) eN = N_EDGES;
    int cnt = eN - e0;

    for (int j = t; j < NBUCK_C; j += 512) {   // bases + derived counts
        int b0 = (int)tbl[(size_t)j * NBLK + blk];
        int b1 = (blk == NBLK - 1) ? off[4 * (j + 1)]       // <= off[3128], valid
                                   : (int)tbl[(size_t)j * NBLK + blk + 1];
        gbase[j] = b0;
        cur[j] = b1 - b0;                      // count
    }
    __syncthreads();
    {   // pairwise shfl exclusive scan over 1024 positions (NBUCK_C live)
        int i0 = 2 * t, i1 = 2 * t + 1;
        int v0 = (i0 < NBUCK_C) ? cur[i0] : 0;
        int v1 = (i1 < NBUCK_C) ? cur[i1] : 0;
        int p = v0 + v1, ps = p;
        #pragma unroll
        for (int d = 1; d < 64; d <<= 1) {
            int u = __shfl_up(ps, d, 64);
            if ((t & 63) >= d) ps += u;
        }
        if ((t & 63) == 63) wsum[t >> 6] = ps;
        __syncthreads();
        int wid = t >> 6, wbase = 0;
        #pragma unroll
        for (int k = 0; k < 8; ++k) wbase += (k < wid) ? wsum[k] : 0;
        int ex = wbase + ps - p;
        if (i0 < NBUCK_C) { sc[i0] = ex;      cur[i0] = ex; }
        if (i1 < NBUCK_C) { sc[i1] = ex + v0; cur[i1] = ex + v0; }
    }
    __syncthreads();
    {   // single edge pass: int4 loads, LDS scatter by coarse bucket
        int nch = cnt >> 2;
        const int4*   c4p = (const int4*)(col + e0);
        const int4*   r4p = (const int4*)(row + e0);
        const float4* w4p = (const float4*)(w + e0);
        for (int i = t; i < nch; i += 512) {
            int4 c = c4p[i]; int4 r = r4p[i]; float4 ww = w4p[i];
            int pos;
            pos = atomicAdd(&cur[c.x >> 7], 1);
            sbuf[pos] = ((unsigned long long)(unsigned)c.x << 47)
                      | ((unsigned long long)(unsigned)r.x << 30)
                      | (unsigned long long)(__float_as_uint(ww.x) >> 2);
            pos = atomicAdd(&cur[c.y >> 7], 1);
            sbuf[pos] = ((unsigned long long)(unsigned)c.y << 47)
                      | ((unsigned long long)(unsigned)r.y << 30)
                      | (unsigned long long)(__float_as_uint(ww.y) >> 2);
            pos = atomicAdd(&cur[c.z >> 7], 1);
            sbuf[pos] = ((unsigned long long)(unsigned)c.z << 47)
                      | ((unsigned long long)(unsigned)r.z << 30)
                      | (unsigned long long)(__float_as_uint(ww.z) >> 2);
            pos = atomicAdd(&cur[c.w >> 7], 1);
            sbuf[pos] = ((unsigned long long)(unsigned)c.w << 47)
                      | ((unsigned long long)(unsigned)r.w << 30)
                      | (unsigned long long)(__float_as_uint(ww.w) >> 2);
        }
    }
    __syncthreads();
    for (int i = t; i < cnt; i += 512) {       // dense sweep; bucket from entry
        unsigned long long pv = sbuf[i];
        int b = (int)(pv >> 54);               // col>>7
        __builtin_nontemporal_store(pv, &packed[gbase[b] + (i - sc[b])]);
    }
}

// S += w*sin_r, C += w*cos_r for 4 dims (lane q of a node group)
__device__ inline void acc_sc(float4& S, float4& C, unsigned long long p,
                              nvec4 h) {
    float we = __uint_as_float(((unsigned)p & 0x3FFFFFFFu) << 2);
    union { nvec4 f; __half2 h2[4]; } uu; uu.f = h;
    float2 f0 = __half22float2(uu.h2[0]);
    float2 f1 = __half22float2(uu.h2[1]);
    float2 f2 = __half22float2(uu.h2[2]);
    float2 f3 = __half22float2(uu.h2[3]);
    S.x += we * f0.x; C.x += we * f0.y;
    S.y += we * f1.x; C.y += we * f1.y;
    S.z += we * f2.x; C.z += we * f2.y;
    S.w += we * f3.x; C.w += we * f3.y;
}

// ---- 5) aggregate: fine bucket reads parent coarse range, filters its
//         quarter. 512 thr = 32 nodes x 4 dim-lanes x 4 edge-subgroups. ----
__global__ __launch_bounds__(512, 8)
void aggregate(const float* __restrict__ state, const float* __restrict__ scp,
               const int* __restrict__ off,
               const unsigned long long* __restrict__ packed,
               float* __restrict__ out) {
    __shared__ unsigned long long sbuf[CAP];       // 12,288 B
    __shared__ nvec4 stage[3 * NPB * 4];           // 6,144 B epilogue staging
    __shared__ int s_cnt[NPB], s_start[NPB], s_cur[NPB];
    int s = blockIdx.x, t = threadIdx.x;
    // XCD-swizzle: co-locate the 4 siblings of a coarse bucket on one XCD
    int b = (s < 3104) ? ((s & ~31) | ((s & 7) << 2) | ((s >> 3) & 3)) : s;
    int q = t & 3, sub = (t >> 2) & 3, g = t >> 4;   // node group 0..31
    unsigned quarter = (unsigned)(b & 3);
    int cb = b >> 2;
    int cbeg = off[cb * 4], cend = off[cb * 4 + 4];  // <= off[3128], valid
    int n = b * NPB + g;                              // always < 100000
    float4 xx = ((const float4*)state)[n * 4 + q];
    float4 S = {0.f, 0.f, 0.f, 0.f}, C = {0.f, 0.f, 0.f, 0.f};
    const nvec4* scp4 = (const nvec4*)scp;

    for (int tbeg = cbeg; tbeg < cend; tbeg += CAP) {
        int tend = tbeg + CAP; if (tend > cend) tend = cend;
        if (t < NPB) s_cnt[t] = 0;
        __syncthreads();

        // phase 1: coalesced read (L2-shared with 3 siblings), filter quarter
        unsigned long long pr[PRK];
        unsigned vm = 0;
        #pragma unroll
        for (int k = 0; k < PRK; ++k) {
            int e = tbeg + t + k * 512;
            if (e < tend) {
                unsigned long long p = packed[e];
                if (((unsigned)(p >> 52) & 3u) == quarter) {
                    pr[k] = p; vm |= 1u << k;
                    atomicAdd(&s_cnt[(unsigned)(p >> 47) & 31u], 1);
                }
            }
        }
        __syncthreads();

        // phase 2: 32-entry exclusive scan on first wave
        if (t < 32) {
            int v = s_cnt[t], ps = v;
            #pragma unroll
            for (int d = 1; d < 32; d <<= 1) {
                int uu = __shfl_up(ps, d, 64);
                if (t >= d) ps += uu;
            }
            s_start[t] = ps - v;
            s_cur[t] = ps - v;
        }
        __syncthreads();

        // phase 3: scatter kept entries from registers
        #pragma unroll
        for (int k = 0; k < PRK; ++k) {
            if ((vm >> k) & 1u) {
                int cl = (int)((pr[k] >> 47) & 31u);
                int pos = atomicAdd(&s_cur[cl], 1);
                sbuf[pos] = pr[k];
            }
        }
        __syncthreads();

        // phase 4: owner-computes; subgroup takes every 4th edge, unroll-4
        {
            int es = s_start[g], ee = s_cur[g];
            int e = es + sub;
            for (; e + 12 < ee; e += 16) {
                unsigned long long p0 = sbuf[e];
                unsigned long long p1 = sbuf[e + 4];
                unsigned long long p2 = sbuf[e + 8];
                unsigned long long p3 = sbuf[e + 12];
                nvec4 h0 = scp4[(unsigned)((p0 >> 30) & 0x1FFFFu) * 4u + q];
                nvec4 h1 = scp4[(unsigned)((p1 >> 30) & 0x1FFFFu) * 4u + q];
                nvec4 h2 = scp4[(unsigned)((p2 >> 30) & 0x1FFFFu) * 4u + q];
                nvec4 h3 = scp4[(unsigned)((p3 >> 30) & 0x1FFFFu) * 4u + q];
                acc_sc(S, C, p0, h0);
                acc_sc(S, C, p1, h1);
                acc_sc(S, C, p2, h2);
                acc_sc(S, C, p3, h3);
            }
            for (; e < ee; e += 4) {
                unsigned long long p0 = sbuf[e];
                nvec4 h0 = scp4[(unsigned)((p0 >> 30) & 0x1FFFFu) * 4u + q];
                acc_sc(S, C, p0, h0);
            }
        }
        __syncthreads();
    }

    // merge 4 subgroups (lanes t^4, t^8 — same wave)
    S.x += __shfl_xor(S.x, 4, 64); S.y += __shfl_xor(S.y, 4, 64);
    S.z += __shfl_xor(S.z, 4, 64); S.w += __shfl_xor(S.w, 4, 64);
    C.x += __shfl_xor(C.x, 4, 64); C.y += __shfl_xor(C.y, 4, 64);
    C.z += __shfl_xor(C.z, 4, 64); C.w += __shfl_xor(C.w, 4, 64);
    S.x += __shfl_xor(S.x, 8, 64); S.y += __shfl_xor(S.y, 8, 64);
    S.z += __shfl_xor(S.z, 8, 64); S.w += __shfl_xor(S.w, 8, 64);
    C.x += __shfl_xor(C.x, 8, 64); C.y += __shfl_xor(C.y, 8, 64);
    C.z += __shfl_xor(C.z, 8, 64); C.w += __shfl_xor(C.w, 8, 64);

    if (sub == 0) {
        // agg = cos(x_c)*S - sin(x_c)*C  (f32 sincos of f32 state)
        float4 agg, th;
        float sx, cx;
        sx = __sinf(xx.x); cx = __cosf(xx.x); agg.x = cx * S.x - sx * C.x;
        sx = __sinf(xx.y); cx = __cosf(xx.y); agg.y = cx * S.y - sx * C.y;
        sx = __sinf(xx.z); cx = __cosf(xx.z); agg.z = cx * S.z - sx * C.z;
        sx = __sinf(xx.w); cx = __cosf(xx.w); agg.w = cx * S.w - sx * C.w;
        th.x = tanhf(agg.x); th.y = tanhf(agg.y);
        th.z = tanhf(agg.z); th.w = tanhf(agg.w);
        int slot = g * 4 + q;                         // 0..127
        stage[0 * 128 + slot] = (nvec4){th.x - xx.x, th.y - xx.y,
                                        th.z - xx.z, th.w - xx.w};
        stage[1 * 128 + slot] = (nvec4){agg.x, agg.y, agg.z, agg.w};
        stage[2 * 128 + slot] = (nvec4){th.x, th.y, th.z, th.w};
    }
    __syncthreads();
    if (t < 384) {                                    // full-density burst write
        int a = t >> 7, j = t & 127;
        nvec4 v = stage[t];
        size_t arr = (a == 0) ? 0 : ((a == 1) ? 3 : 4);
        __builtin_nontemporal_store(
            v, &((nvec4*)(out + arr * (size_t)NSZ))[b * 128 + j]);
    }
}

// ---- fallback (tiny ws): atomic path ----
__global__ __launch_bounds__(256)
void edge_kernel(const float* __restrict__ state, const int* __restrict__ row,
                 const int* __restrict__ col, const float* __restrict__ w,
                 float* __restrict__ agg) {
    int idx = blockIdx.x * blockDim.x + threadIdx.x;
    if (idx >= N_EDGES * 4) return;
    int e = idx >> 2, qq = idx & 3;
    int r = row[e], c = col[e];
    float we = w[e];
    const float4 xr = ((const float4*)state)[r * 4 + qq];
    const float4 xcv = ((const float4*)state)[c * 4 + qq];
    float* dst = agg + c * DIM + qq * 4;
    atomicAdd(dst + 0, sinf(xr.x - xcv.x) * we);
    atomicAdd(dst + 1, sinf(xr.y - xcv.y) * we);
    atomicAdd(dst + 2, sinf(xr.z - xcv.z) * we);
    atomicAdd(dst + 3, sinf(xr.w - xcv.w) * we);
}

__global__ __launch_bounds__(256)
void node_kernel(const float* __restrict__ state, const float* __restrict__ agg,
                 float* __restrict__ out) {
    int idx = blockIdx.x * blockDim.x + threadIdx.x;
    if (idx >= N_NODES * 4) return;
    float4 x = ((const float4*)state)[idx];
    float4 a = ((const float4*)agg)[idx];
    float4 tv = make_float4(tanhf(a.x), tanhf(a.y), tanhf(a.z), tanhf(a.w));
    ((float4*)(out + 0 * NSZ))[idx] = make_float4(tv.x - x.x, tv.y - x.y,
                                                  tv.z - x.z, tv.w - x.w);
    ((float4*)(out + 1 * NSZ))[idx] = x;
    ((float4*)(out + 2 * NSZ))[idx] = make_float4(-x.x, -x.y, -x.z, -x.w);
    ((float4*)(out + 4 * NSZ))[idx] = tv;
}

extern "C" void kernel_launch(void* const* d_in, const int* in_sizes, int n_in,
                              void* d_out, int out_size, void* d_ws, size_t ws_size,
                              hipStream_t stream) {
    const float* state = (const float*)d_in[0];
    const int*   row   = (const int*)d_in[1];
    const int*   col   = (const int*)d_in[2];
    const float* w     = (const float*)d_in[3];
    float* out = (float*)d_out;

    // ws: packed | scp (f16 sincos) | tbl | totals | off (3129 entries + pad)
    size_t packed_off = 0;
    size_t scp_off    = packed_off + (size_t)N_EDGES * 8;          // 25.6MB
    size_t tbl_off    = scp_off + (size_t)NSZ * 4;                 // +6.4MB
    size_t tot_off    = tbl_off + (size_t)NBUCK_C * NBLK * 4;      // +1.6MB
    size_t off_off    = tot_off + ((size_t)NBUCK_F * 4 + 15) / 16 * 16;
    size_t needed     = off_off + (size_t)(OFFMAX + 2) * 4;

    if (ws_size >= needed) {
        unsigned long long* packed =
            (unsigned long long*)((char*)d_ws + packed_off);
        float* scp    = (float*)((char*)d_ws + scp_off);
        unsigned* tbl = (unsigned*)((char*)d_ws + tbl_off);
        int* totals   = (int*)((char*)d_ws + tot_off);
        int* off      = (int*)((char*)d_ws + off_off);

        (void)hipMemsetAsync(totals, 0, (size_t)NBUCK_F * sizeof(int), stream);
        prep<<<NBLK, 512, 0, stream>>>(state, col, scp, out, tbl, totals);
        scan_off<<<1, 1024, 0, stream>>>(totals, off);
        base_scan<<<NBUCK_C, 512, 0, stream>>>(tbl, off);
        sort_write<<<NBLK, 512, 0, stream>>>(row, col, w, tbl, off, packed);
        aggregate<<<NBUCK_F, 512, 0, stream>>>(state, scp, off, packed, out);
    } else {
        float* agg = out + 3 * NSZ;
        (void)hipMemsetAsync(agg, 0, NSZ * sizeof(float), stream);
        edge_kernel<<<(N_EDGES * 4 + 255) / 256, 256, 0, stream>>>(
            state, row, col, w, agg);
        node_kernel<<<(N_NODES * 4 + 255) / 256, 256, 0, stream>>>(
            state, agg, out);
    }
}